// Round 1
// baseline (123.804 us; speedup 1.0000x reference)
//
#include <hip/hip_runtime.h>

// 10 qubits: 1024 amplitudes. One wave (64 lanes) per batch element.
// k = (lane << 4) | m ; bits 0..3 local (register index m), bits 4..9 = lane.
// Qubit j corresponds to bit P = 9 - j of k (qubit 0 is MSB per reference reshape).

#define NQ 10

// RX gate on bit P of k. U = [[c, -i s],[-i s, c]] (symmetric):
//   new = c*a + (-i*s)*b  ->  re: c*a.x + s*b.y ; im: c*a.y - s*b.x
template<int P>
__device__ __forceinline__ void rx_gate(float2 (&amp)[16], float half_t) {
    const float c = __cosf(half_t);
    const float s = __sinf(half_t);
    if constexpr (P < 4) {
        constexpr int bit = 1 << P;
        #pragma unroll
        for (int m = 0; m < 16; ++m) {
            if ((m & bit) == 0) {
                const float2 a = amp[m];
                const float2 b = amp[m | bit];
                amp[m]       = make_float2(fmaf(c, a.x,  s * b.y), fmaf(c, a.y, -s * b.x));
                amp[m | bit] = make_float2(fmaf(c, b.x,  s * a.y), fmaf(c, b.y, -s * a.x));
            }
        }
    } else {
        constexpr int lmask = 1 << (P - 4);
        #pragma unroll
        for (int m = 0; m < 16; ++m) {
            const float bx = __shfl_xor(amp[m].x, lmask, 64);
            const float by = __shfl_xor(amp[m].y, lmask, 64);
            amp[m] = make_float2(fmaf(c, amp[m].x,  s * by),
                                 fmaf(c, amp[m].y, -s * bx));
        }
    }
}

// CNOT: control bit PC, target bit PT of k. If control bit set, flip target bit.
template<int PC, int PT>
__device__ __forceinline__ void cnot_gate(float2 (&amp)[16], int lane) {
    if constexpr (PC < 4 && PT < 4) {
        // both local: register permutation
        constexpr int cbit = 1 << PC, tbit = 1 << PT;
        #pragma unroll
        for (int m = 0; m < 16; ++m) {
            if ((m & cbit) && !(m & tbit)) {
                const float2 t = amp[m];
                amp[m] = amp[m | tbit];
                amp[m | tbit] = t;
            }
        }
    } else if constexpr (PC < 4 && PT >= 4) {
        // control local, target cross-lane: swap across lanes for control-set m
        constexpr int cbit = 1 << PC;
        constexpr int lmask = 1 << (PT - 4);
        #pragma unroll
        for (int m = 0; m < 16; ++m) {
            if (m & cbit) {
                amp[m].x = __shfl_xor(amp[m].x, lmask, 64);
                amp[m].y = __shfl_xor(amp[m].y, lmask, 64);
            }
        }
    } else if constexpr (PC >= 4 && PT < 4) {
        // control cross-lane, target local: conditional register swap
        constexpr int tbit = 1 << PT;
        const bool ctrl = (lane >> (PC - 4)) & 1;
        #pragma unroll
        for (int m = 0; m < 16; ++m) {
            if ((m & tbit) == 0) {
                const float2 a = amp[m];
                const float2 b = amp[m | tbit];
                amp[m]        = ctrl ? b : a;
                amp[m | tbit] = ctrl ? a : b;
            }
        }
    } else {
        // both cross-lane: partner lane has the same control bit (PC != PT),
        // so unconditional shfl + select is a correct pairwise swap.
        constexpr int lmask = 1 << (PT - 4);
        const bool ctrl = (lane >> (PC - 4)) & 1;
        #pragma unroll
        for (int m = 0; m < 16; ++m) {
            const float vx = __shfl_xor(amp[m].x, lmask, 64);
            const float vy = __shfl_xor(amp[m].y, lmask, 64);
            if (ctrl) { amp[m].x = vx; amp[m].y = vy; }
        }
    }
}

#define RX_LAYER(p) \
    rx_gate<9>(amp, 0.5f * (p)[0]); rx_gate<8>(amp, 0.5f * (p)[1]); \
    rx_gate<7>(amp, 0.5f * (p)[2]); rx_gate<6>(amp, 0.5f * (p)[3]); \
    rx_gate<5>(amp, 0.5f * (p)[4]); rx_gate<4>(amp, 0.5f * (p)[5]); \
    rx_gate<3>(amp, 0.5f * (p)[6]); rx_gate<2>(amp, 0.5f * (p)[7]); \
    rx_gate<1>(amp, 0.5f * (p)[8]); rx_gate<0>(amp, 0.5f * (p)[9])

#define CNOT_RING() \
    cnot_gate<9, 8>(amp, lane); cnot_gate<8, 7>(amp, lane); \
    cnot_gate<7, 6>(amp, lane); cnot_gate<6, 5>(amp, lane); \
    cnot_gate<5, 4>(amp, lane); cnot_gate<4, 3>(amp, lane); \
    cnot_gate<3, 2>(amp, lane); cnot_gate<2, 1>(amp, lane); \
    cnot_gate<1, 0>(amp, lane); cnot_gate<0, 9>(amp, lane)

__global__ __launch_bounds__(256)
void qsim_kernel(const float* __restrict__ inputs,
                 const float* __restrict__ weights,
                 float* __restrict__ out, int B) {
    const int gid  = blockIdx.x * blockDim.x + threadIdx.x;
    const int wave = gid >> 6;
    const int lane = threadIdx.x & 63;
    if (wave >= B) return;

    // |0...0> : amplitude k=0 is 1
    float2 amp[16];
    #pragma unroll
    for (int m = 0; m < 16; ++m) amp[m] = make_float2(0.f, 0.f);
    amp[0].x = (lane == 0) ? 1.0f : 0.0f;

    const float* in = inputs + wave * NQ;
    RX_LAYER(in);

    // layer 0
    RX_LAYER(weights + 0 * NQ);
    CNOT_RING();
    // layer 1
    RX_LAYER(weights + 1 * NQ);
    CNOT_RING();

    // Z-expectations: out[b,q] = sum_k p_k * (1 - 2*bit(k, 9-q))
    float tot = 0.f, sb0 = 0.f, sb1 = 0.f, sb2 = 0.f, sb3 = 0.f;
    #pragma unroll
    for (int m = 0; m < 16; ++m) {
        const float p = fmaf(amp[m].x, amp[m].x, amp[m].y * amp[m].y);
        tot += p;
        if (m & 1) sb0 += p;
        if (m & 2) sb1 += p;
        if (m & 4) sb2 += p;
        if (m & 8) sb3 += p;
    }

    float acc[10];
    #pragma unroll
    for (int q = 0; q < 6; ++q)   // bit 9-q is a lane bit (5-q)
        acc[q] = ((lane >> (5 - q)) & 1) ? -tot : tot;
    acc[6] = tot - 2.f * sb3;     // bit 3
    acc[7] = tot - 2.f * sb2;     // bit 2
    acc[8] = tot - 2.f * sb1;     // bit 1
    acc[9] = tot - 2.f * sb0;     // bit 0

    // butterfly reduce across the wave (all lanes end with full sums)
    #pragma unroll
    for (int off = 32; off >= 1; off >>= 1) {
        #pragma unroll
        for (int q = 0; q < 10; ++q)
            acc[q] += __shfl_xor(acc[q], off, 64);
    }

    // coalesced store: lane q writes acc[q]
    float v = 0.f;
    #pragma unroll
    for (int q = 0; q < 10; ++q)
        if (lane == q) v = acc[q];
    if (lane < 10) out[wave * NQ + lane] = v;
}

extern "C" void kernel_launch(void* const* d_in, const int* in_sizes, int n_in,
                              void* d_out, int out_size, void* d_ws, size_t ws_size,
                              hipStream_t stream) {
    const float* inputs  = (const float*)d_in[0];
    const float* weights = (const float*)d_in[1];
    float* out = (float*)d_out;
    const int B = in_sizes[0] / NQ;          // 8192
    const int waves_per_block = 4;           // 256 threads
    const int blocks = (B + waves_per_block - 1) / waves_per_block;
    qsim_kernel<<<blocks, 256, 0, stream>>>(inputs, weights, out, B);
}

// Round 2
// 79.595 us; speedup vs baseline: 1.5554x; 1.5554x over previous
//
#include <hip/hip_runtime.h>

// 10 qubits, 1024 amps, one wave per batch element.
// Physical slot p = (lane << 4) | m : bits 0..3 = register index m, bits 4..9 = lane.
// Qubit j <-> logical bit b = 9 - j.
//
// CNOT rings are applied LAZILY as a GF(2) relabeling: slot p holds the amplitude
// of logical index A*p. CNOT(c,t) updates A <- C*A (compile-time bookkeeping only).
// RX on logical bit b pairs slots p and p ^ (A^-1 e_b). After ring 1:
//   A1^-1 columns (pair masks): b=9:{8,9} b=8:{7,8} b=7:{6,7} b=6:{5,6} b=5:{4,5}
//   b=4:{3,4} b=3:{2,3} b=2:{1,2} b=1:{0,1} b=0:{0,8,9}
// After ring 2, logical bit b of slot p = parity(row_b(A2) & p):
//   r9=0x355 r8=0x2FF r7=0x17F r6=0x2BF r5=0x15F r4=0x2AF r3=0x157 r2=0x2AB r1=0x155 r0=0x2AA

#define NQ 10

// Cross-lane xor move. DPP (VALU pipe) for masks 1,2,3,8; ds_swizzle for other
// masks < 32; ds_bpermute (precomputed byte address) for masks with bit 32.
template<int LMASK>
__device__ __forceinline__ float lxor(float x, int a32, int a48) {
    if constexpr (LMASK == 1)        // quad_perm [1,0,3,2]
        return __int_as_float(__builtin_amdgcn_update_dpp(
            __float_as_int(x), __float_as_int(x), 0xB1, 0xF, 0xF, true));
    else if constexpr (LMASK == 2)   // quad_perm [2,3,0,1]
        return __int_as_float(__builtin_amdgcn_update_dpp(
            __float_as_int(x), __float_as_int(x), 0x4E, 0xF, 0xF, true));
    else if constexpr (LMASK == 3)   // quad_perm [3,2,1,0]
        return __int_as_float(__builtin_amdgcn_update_dpp(
            __float_as_int(x), __float_as_int(x), 0x1B, 0xF, 0xF, true));
    else if constexpr (LMASK == 8)   // row_ror:8 == xor 8 within 16-lane rows
        return __int_as_float(__builtin_amdgcn_update_dpp(
            __float_as_int(x), __float_as_int(x), 0x128, 0xF, 0xF, true));
    else if constexpr (LMASK == 32)
        return __int_as_float(__builtin_amdgcn_ds_bpermute(a32, __float_as_int(x)));
    else if constexpr (LMASK == 48)
        return __int_as_float(__builtin_amdgcn_ds_bpermute(a48, __float_as_int(x)));
    else                             // xor within 32-lane halves
        return __int_as_float(__builtin_amdgcn_ds_swizzle(
            __float_as_int(x), (LMASK << 10) | 0x1F));
}

// RX pairing slots p and p ^ ((LMASK<<4) | RMASK), LMASK != 0.
// U = [[c,-is],[-is,c]] is symmetric: new = c*a + (-i s)*partner for BOTH sides,
// so every slot applies the same formula. Snapshot partners first (RMASK aliasing).
template<int LMASK, int RMASK>
__device__ __forceinline__ void rx_lane(float2 (&A)[16], float c, float s,
                                        int a32, int a48) {
    float px[16], py[16];
    #pragma unroll
    for (int m = 0; m < 16; ++m) px[m] = lxor<LMASK>(A[m ^ RMASK].x, a32, a48);
    #pragma unroll
    for (int m = 0; m < 16; ++m) py[m] = lxor<LMASK>(A[m ^ RMASK].y, a32, a48);
    #pragma unroll
    for (int m = 0; m < 16; ++m)
        A[m] = make_float2(fmaf(c, A[m].x,  s * py[m]),
                           fmaf(c, A[m].y, -s * px[m]));
}

// RX with purely in-register pairing (mask RMASK over m).
template<int RMASK>
__device__ __forceinline__ void rx_local(float2 (&A)[16], float c, float s) {
    #pragma unroll
    for (int m = 0; m < 16; ++m) {
        const int pm = m ^ RMASK;
        if (m < pm) {
            const float2 a = A[m], b = A[pm];
            A[m]  = make_float2(fmaf(c, a.x,  s * b.y), fmaf(c, a.y, -s * b.x));
            A[pm] = make_float2(fmaf(c, b.x,  s * a.y), fmaf(c, b.y, -s * a.x));
        }
    }
}

__global__ __launch_bounds__(256)
void qsim_kernel(const float* __restrict__ inputs,
                 const float* __restrict__ weights,
                 float* __restrict__ out, int B) {
    const int gid  = blockIdx.x * blockDim.x + threadIdx.x;
    const int wave = gid >> 6;
    const int lane = threadIdx.x & 63;
    if (wave >= B) return;

    const int a32 = ((lane ^ 32) << 2);   // ds_bpermute byte addrs
    const int a48 = ((lane ^ 48) << 2);

    float2 A[16];
    #pragma unroll
    for (int m = 0; m < 16; ++m) A[m] = make_float2(0.f, 0.f);
    A[0].x = (lane == 0) ? 1.0f : 0.0f;

    const float* in = inputs + wave * NQ;
    float c, s;
    #define CS(t) __sincosf(0.5f * (t), &s, &c)

    // ---- layer 0 (input angles) + layer 1 (weights row 0): A = I, masks e_b ----
    #define PLAIN_LAYER(P) \
        CS((P)[0]); rx_lane<32,0>(A, c, s, a32, a48); \
        CS((P)[1]); rx_lane<16,0>(A, c, s, a32, a48); \
        CS((P)[2]); rx_lane< 8,0>(A, c, s, a32, a48); \
        CS((P)[3]); rx_lane< 4,0>(A, c, s, a32, a48); \
        CS((P)[4]); rx_lane< 2,0>(A, c, s, a32, a48); \
        CS((P)[5]); rx_lane< 1,0>(A, c, s, a32, a48); \
        CS((P)[6]); rx_local<8>(A, c, s); \
        CS((P)[7]); rx_local<4>(A, c, s); \
        CS((P)[8]); rx_local<2>(A, c, s); \
        CS((P)[9]); rx_local<1>(A, c, s)

    PLAIN_LAYER(in);
    PLAIN_LAYER(weights);
    // (ring 1 is free: A <- Ring*A)

    // ---- layer 2 (weights row 1): masks = A1^-1 columns ----
    {
        const float* w = weights + NQ;
        CS(w[0]); rx_lane<48,0>(A, c, s, a32, a48);   // {8,9}
        CS(w[1]); rx_lane<24,0>(A, c, s, a32, a48);   // {7,8}
        CS(w[2]); rx_lane<12,0>(A, c, s, a32, a48);   // {6,7}
        CS(w[3]); rx_lane< 6,0>(A, c, s, a32, a48);   // {5,6}
        CS(w[4]); rx_lane< 3,0>(A, c, s, a32, a48);   // {4,5}
        CS(w[5]); rx_lane< 1,8>(A, c, s, a32, a48);   // {3,4}
        CS(w[6]); rx_local<12>(A, c, s);              // {2,3}
        CS(w[7]); rx_local< 6>(A, c, s);              // {1,2}
        CS(w[8]); rx_local< 3>(A, c, s);              // {0,1}
        CS(w[9]); rx_lane<48,1>(A, c, s, a32, a48);   // {0,8,9}
    }
    // (ring 2 free)

    // ---- measurement: out[b,q] = sum_p |amp[p]|^2 * (1-2*parity(r_{9-q} & p)) ----
    float p[16];
    #pragma unroll
    for (int m = 0; m < 16; ++m)
        p[m] = fmaf(A[m].x, A[m].x, A[m].y * A[m].y);

    // distinct register-bit sign sums (r & 0xF): 0xF, 0x5, 0x7, 0xB, 0xA
    float SF = 0.f, S5 = 0.f, S7 = 0.f, SB = 0.f, SA = 0.f;
    #pragma unroll
    for (int m = 0; m < 16; ++m) {
        SF += (__popc(m & 0xF) & 1) ? -p[m] : p[m];
        S5 += (__popc(m & 0x5) & 1) ? -p[m] : p[m];
        S7 += (__popc(m & 0x7) & 1) ? -p[m] : p[m];
        SB += (__popc(m & 0xB) & 1) ? -p[m] : p[m];
        SA += (__popc(m & 0xA) & 1) ? -p[m] : p[m];
    }

    // q -> (lane mask of r_{9-q}, reg sum)
    float acc[10];
    {
        const float Sv[10]  = { S5, SF, SF, SF, SF, SF, S7, SB, S5, SA };
        const int   lm[10]  = { 0x35, 0x2F, 0x17, 0x2B, 0x15, 0x2A,
                                0x15, 0x2A, 0x15, 0x2A };
        #pragma unroll
        for (int q = 0; q < 10; ++q)
            acc[q] = (__popc(lane & lm[q]) & 1) ? -Sv[q] : Sv[q];
    }

    // butterfly reduce across 64 lanes (DPP for 1,2,8; ds for 4,16,32)
    #pragma unroll
    for (int q = 0; q < 10; ++q) acc[q] += lxor< 1>(acc[q], a32, a48);
    #pragma unroll
    for (int q = 0; q < 10; ++q) acc[q] += lxor< 2>(acc[q], a32, a48);
    #pragma unroll
    for (int q = 0; q < 10; ++q) acc[q] += lxor< 4>(acc[q], a32, a48);
    #pragma unroll
    for (int q = 0; q < 10; ++q) acc[q] += lxor< 8>(acc[q], a32, a48);
    #pragma unroll
    for (int q = 0; q < 10; ++q) acc[q] += lxor<16>(acc[q], a32, a48);
    #pragma unroll
    for (int q = 0; q < 10; ++q) acc[q] += lxor<32>(acc[q], a32, a48);

    float v = 0.f;
    #pragma unroll
    for (int q = 0; q < 10; ++q)
        if (lane == q) v = acc[q];
    if (lane < 10) out[wave * NQ + lane] = v;
}

extern "C" void kernel_launch(void* const* d_in, const int* in_sizes, int n_in,
                              void* d_out, int out_size, void* d_ws, size_t ws_size,
                              hipStream_t stream) {
    const float* inputs  = (const float*)d_in[0];
    const float* weights = (const float*)d_in[1];
    float* out = (float*)d_out;
    const int B = in_sizes[0] / NQ;          // 8192
    const int blocks = (B + 3) / 4;          // 4 waves / block
    qsim_kernel<<<blocks, 256, 0, stream>>>(inputs, weights, out, B);
}